// Round 5
// baseline (214.609 us; speedup 1.0000x reference)
//
#include <hip/hip_runtime.h>
#include <stdint.h>

#define ROWS   4096
#define NCOL   8192
#define TARGET 7680
#define NW     (NCOL - TARGET + 1)   // 513 windows
#define NT     512                   // threads per block (8 waves)
#define VPT    (NCOL / NT)           // 16 values per thread (in VGPRs)
#define NB     2048                  // histogram bins
#define BPT    (NB / NT)             // 4 bins per thread in scan
#define NWAVE  (NT / 64)             // 8 waves
#define SCAP   2048                  // sorted-buffer capacity (typ. tot ~1030)
#define MAXS   (SCAP / NT)           // max slots per thread in fixup (4)
#define RPB    4                     // rows per block (software pipeline depth)
#define GRID   (ROWS / RPB)          // 1024 blocks

struct Smem {
    uint32_t hist[NB];       // transposed: logical bin b at ((b&3)<<9)|(b>>2)
    float    sorted[SCAP];   // scattered candidates (unordered within bin)
    float    sorted2[SCAP];  // fixup output: exact sorted tails
    uint32_t wsum[NWAVE];
    uint32_t res[4];         // [0]=B_lo [1]=cntB(incl) [2]=B_hi [3]=topBase(excl)
    float    fmin[NWAVE], fmax[NWAVE];
    float    rv[NWAVE];
    int      ri[NWAVE];
};

__device__ __forceinline__ int bin1f(float v, float mn, float s) {
    int b = (int)((v - mn) * s);
    return b < 0 ? 0 : (b > NB - 1 ? NB - 1 : b);
}
// transposed physical index: scan reads hist[(j<<9)|tid] lane-consecutively
// (conflict-free); atomics hash on bin bits 2..6 (random for random values).
__device__ __forceinline__ int HIX(int b) { return ((b & 3) << 9) | (b >> 2); }

// Issue a full row load into registers. No dependent use here, so the
// global_load_dwordx4s stay in flight until the consumer (or a barrier
// drain) waits on them -- this is the prefetch primitive.
__device__ __forceinline__ void load_row(const float* __restrict__ x, int row,
                                         int tid, float (&v)[VPT]) {
    const float4* xv = (const float4*)(x + (size_t)row * NCOL);
    #pragma unroll
    for (int j = 0; j < VPT / 4; j++) {
        float4 t = xv[tid + j * NT];
        v[4 * j + 0] = t.x; v[4 * j + 1] = t.y;
        v[4 * j + 2] = t.z; v[4 * j + 3] = t.w;
    }
}

__device__ __forceinline__ void process_row(Smem& sm, const float (&v)[VPT],
                                            float* __restrict__ out, int row,
                                            int tid, int lane, int wid) {
    // ---- Block min/max (+ zero hist in same phase) ----
    float mn = v[0], mx = v[0];
    #pragma unroll
    for (int j = 1; j < VPT; j++) { mn = fminf(mn, v[j]); mx = fmaxf(mx, v[j]); }
    #pragma unroll
    for (int off = 32; off > 0; off >>= 1) {
        mn = fminf(mn, __shfl_down(mn, off, 64));
        mx = fmaxf(mx, __shfl_down(mx, off, 64));
    }
    if (lane == 0) { sm.fmin[wid] = mn; sm.fmax[wid] = mx; }
    #pragma unroll
    for (int j = 0; j < BPT; j++) sm.hist[tid + j * NT] = 0;
    __syncthreads();                                             // S1
    #pragma unroll
    for (int w = 0; w < NWAVE; w++) {
        mn = fminf(mn, sm.fmin[w]);
        mx = fmaxf(mx, sm.fmax[w]);
    }

    if (!(mx > mn)) {   // all values equal (uniform branch; barriers skipped uniformly)
        if (tid == 0) { out[row] = mn; out[ROWS + row] = mn; }
        return;
    }
    const float scale1 = (float)NB / (mx - mn);

    // ---- L1: value-linear histogram (transposed-layout atomics) ----
    #pragma unroll
    for (int j = 0; j < VPT; j++)
        atomicAdd(&sm.hist[HIX(bin1f(v[j], mn, scale1))], 1u);
    __syncthreads();                                             // S2

    // ---- Single scan: locate rank bins + write scatter bases ----
    uint32_t h[BPT], s0 = 0;
    #pragma unroll
    for (int j = 0; j < BPT; j++) { h[j] = sm.hist[(j << 9) | tid]; s0 += h[j]; }
    uint32_t sc = s0;
    #pragma unroll
    for (int off = 1; off < 64; off <<= 1) {
        uint32_t n = __shfl_up(sc, off, 64);
        if (lane >= off) sc += n;
    }
    if (lane == 63) sm.wsum[wid] = sc;
    __syncthreads();                                             // S3
    uint32_t woff = 0;
    #pragma unroll
    for (int w = 0; w < NWAVE; w++) if (w < wid) woff += sm.wsum[w];
    const uint32_t incl = sc + woff, excl = incl - s0;
    const uint32_t ka = NW - 1, kb = TARGET - 1;
    if (ka >= excl && ka < incl) {           // bin of rank 512 (bottom tail end)
        uint32_t c = excl; bool done = false;
        #pragma unroll
        for (int j = 0; j < BPT; j++) {
            if (!done) {
                if (ka < c + h[j]) {
                    sm.res[0] = (uint32_t)(tid * BPT + j);
                    sm.res[1] = c + h[j];    // cntB = inclusive prefix at B_lo
                    done = true;
                } else c += h[j];
            }
        }
    }
    if (kb >= excl && kb < incl) {           // bin of rank 7679 (top tail start)
        uint32_t c = excl; bool done = false;
        #pragma unroll
        for (int j = 0; j < BPT; j++) {
            if (!done) {
                if (kb < c + h[j]) {
                    sm.res[2] = (uint32_t)(tid * BPT + j);
                    sm.res[3] = c;           // topBase = exclusive prefix at B_hi
                    done = true;
                } else c += h[j];
            }
        }
    }
    {   // overwrite counts with exclusive-prefix bases (independent of res)
        uint32_t run = excl;
        #pragma unroll
        for (int j = 0; j < BPT; j++) { sm.hist[(j << 9) | tid] = run; run += h[j]; }
    }
    __syncthreads();                                             // S4
    const int      B_lo    = (int)sm.res[0];
    const uint32_t cntB    = sm.res[1];
    const int      B_hi    = (int)sm.res[2];
    const uint32_t topBase = sm.res[3];
    const uint32_t shiftT  = cntB - topBase;     // mod-2^32; top slot = excl + shiftT
    uint32_t tot = cntB + (uint32_t)NCOL - topBase;
    if (tot > SCAP) tot = SCAP;

    // ---- Scatter candidates directly to global-rank slots ----
    #pragma unroll
    for (int j = 0; j < VPT; j++) {
        float val = v[j];
        int b = bin1f(val, mn, scale1);
        if (b <= B_lo || b >= B_hi) {
            uint32_t pos = atomicAdd(&sm.hist[HIX(b)], 1u);
            if (b >= B_hi) pos += shiftT;
            if (pos < SCAP) sm.sorted[pos] = val;
        }
    }
    __syncthreads();                                             // S5
    // now hist[b] = exclusive prefix + count = inclusive end (unshifted for top)

    // ---- Fix-up: rank within L1 bins, write to sorted2 (no WB hazard) ----
    #pragma unroll
    for (int it = 0; it < MAXS; it++) {
        int s = tid + it * NT;
        if (s < (int)tot) {
            float vv = sm.sorted[s];
            int b = bin1f(vv, mn, scale1);
            uint32_t en = sm.hist[HIX(b)];
            uint32_t st;
            if (s < (int)cntB) {
                st = (b == 0) ? 0u : sm.hist[HIX(b - 1)];
            } else {
                st = (b == B_hi) ? topBase : sm.hist[HIX(b - 1)];
                st += shiftT; en += shiftT;
            }
            if (en > tot) en = tot;
            uint32_t r = 0;
            if (en - st > 1) {
                for (uint32_t q = st; q < en; q++) {
                    float u = sm.sorted[q];
                    r += (u < vv) || (u == vv && (int)q < s);
                }
            }
            uint32_t d = st + r;
            if (d < SCAP) sm.sorted2[d] = vv;
        }
    }
    __syncthreads();                                             // S6

    // sorted2[0..cntB) = global ranks 0..cntB-1; sorted2[cntB..tot) = top tail.
    // window i: left = sorted2[i]; right = sorted2[tot - NW + i]

    // ---- lengths + first-occurrence argmin ----
    const int topstart = (int)tot - NW;
    float lbest = __int_as_float(0x7F800000);   // +inf
    int   lidx  = 0x7FFFFFFF;
    for (int i = tid; i < NW; i += NT) {
        float len = sm.sorted2[topstart + i] - sm.sorted2[i];
        if (len < lbest) { lbest = len; lidx = i; }
    }
    #pragma unroll
    for (int off = 32; off > 0; off >>= 1) {
        float v2 = __shfl_down(lbest, off, 64);
        int   i2 = __shfl_down(lidx,  off, 64);
        if (v2 < lbest || (v2 == lbest && i2 < lidx)) { lbest = v2; lidx = i2; }
    }
    if (lane == 0) { sm.rv[wid] = lbest; sm.ri[wid] = lidx; }
    __syncthreads();                                             // S7
    if (tid == 0) {
        float bv = sm.rv[0]; int bi = sm.ri[0];
        #pragma unroll
        for (int w = 1; w < NWAVE; w++) {
            float v2 = sm.rv[w]; int i2 = sm.ri[w];
            if (v2 < bv || (v2 == bv && i2 < bi)) { bv = v2; bi = i2; }
        }
        out[row]        = sm.sorted2[bi];             // left  = s[idx]
        out[ROWS + row] = sm.sorted2[topstart + bi];  // right = s[idx+target-1]
    }
    // thread 0's epilogue reads complete before it reaches the next row's S1;
    // next row's first write to sorted2 is 5 barriers later -> no hazard.
}

// launch_bounds(512,4): 128-VGPR budget. (512,8) forced a 64-VGPR budget that
// spilled v[] to scratch (round-3: WRITE_SIZE 3.8->106 MB). Double-buffer adds
// ~16 VGPR; expected ~80-90 total -> no spill, ~3 resident blocks/CU.
__global__ __launch_bounds__(NT, 4)
void recall_window_kernel(const float* __restrict__ x, float* __restrict__ out) {
    __shared__ Smem sm;
    const int tid = threadIdx.x;
    const int lane = tid & 63, wid = tid >> 6;
    const int row0 = blockIdx.x * RPB;

    // Software pipeline: while computing row r (7 barrier phases, each barrier
    // drains vmcnt), the loads for row r+1 are already in flight -> the HBM
    // pipe streams continuously instead of only during the per-row load phase.
    float va[VPT], vb[VPT];
    load_row(x, row0 + 0, tid, va);
    load_row(x, row0 + 1, tid, vb);              // prefetch r+1
    process_row(sm, va, out, row0 + 0, tid, lane, wid);
    load_row(x, row0 + 2, tid, va);              // prefetch r+2
    process_row(sm, vb, out, row0 + 1, tid, lane, wid);
    load_row(x, row0 + 3, tid, vb);              // prefetch r+3
    process_row(sm, va, out, row0 + 2, tid, lane, wid);
    process_row(sm, vb, out, row0 + 3, tid, lane, wid);
}

extern "C" void kernel_launch(void* const* d_in, const int* in_sizes, int n_in,
                              void* d_out, int out_size, void* d_ws, size_t ws_size,
                              hipStream_t stream) {
    const float* x = (const float*)d_in[0];
    float* out = (float*)d_out;
    recall_window_kernel<<<GRID, NT, 0, stream>>>(x, out);
}

// Round 6
// 190.319 us; speedup vs baseline: 1.1276x; 1.1276x over previous
//
#include <hip/hip_runtime.h>
#include <stdint.h>

#define ROWS   4096
#define NCOL   8192
#define TARGET 7680
#define NW     (NCOL - TARGET + 1)   // 513 windows
#define NT     512                   // threads per block (8 waves)
#define VPT    (NCOL / NT)           // 16 values per thread (in VGPRs)
#define NB     2048                  // histogram bins
#define BPT    (NB / NT)             // 4 bins per thread in scan
#define NWAVE  (NT / 64)             // 8 waves
#define SCAP   2048                  // sorted-buffer capacity (typ. tot ~1030)
#define MAXS   (SCAP / NT)           // max slots per thread in fixup (4)

struct Smem {
    uint32_t hist[NB];       // transposed: logical bin b at ((b&3)<<9)|(b>>2)
    float    sorted[SCAP];   // scattered candidates (unordered within bin)
    float    sorted2[SCAP];  // fixup output: exact sorted tails
    uint32_t wsum[NWAVE];
    uint32_t res[4];         // [0]=B_lo [1]=cntB(incl) [2]=B_hi [3]=topBase(excl)
    float    fmin[NWAVE], fmax[NWAVE];
};

// v in [mn,mx] guaranteed (block min/max) -> (v-mn)*s >= 0 exactly; only the
// upper clamp is needed (v==mx lands on NB).
__device__ __forceinline__ int bin1f(float v, float mn, float s) {
    int b = (int)((v - mn) * s);
    return b > NB - 1 ? NB - 1 : b;
}
// transposed physical index: scan reads hist[(j<<9)|tid] lane-consecutively
// (conflict-free); atomics hash on bin bits 2..6 (random for random values).
__device__ __forceinline__ int HIX(int b) { return ((b & 3) << 9) | (b >> 2); }

// launch_bounds(512,4): 128-VGPR budget. (512,8) forced a 64-VGPR budget that
// spilled v[] to scratch (round-3: WRITE_SIZE 3.8->106 MB). Natural allocation
// ~60 VGPR -> 8 waves/EU, no spill. Grid stays 4096 (1 row/block): round-5
// showed RPB=4/1024-block convoys in lockstep and loses 2x.
__global__ __launch_bounds__(NT, 4)
void recall_window_kernel(const float* __restrict__ x, float* __restrict__ out) {
    __shared__ Smem sm;
    const int tid = threadIdx.x;
    const int row = blockIdx.x;
    const int lane = tid & 63, wid = tid >> 6;

    // ---- Load row into registers (coalesced 16B), min/max fused so the
    //      float4 staging temps die immediately (lower peak VGPR) ----
    float v[VPT];
    float mn = __int_as_float(0x7F800000), mx = -mn;
    const float4* xv = (const float4*)(x + (size_t)row * NCOL);
    #pragma unroll
    for (int j = 0; j < VPT / 4; j++) {
        float4 t = xv[tid + j * NT];
        v[4 * j + 0] = t.x; v[4 * j + 1] = t.y;
        v[4 * j + 2] = t.z; v[4 * j + 3] = t.w;
        mn = fminf(mn, fminf(fminf(t.x, t.y), fminf(t.z, t.w)));
        mx = fmaxf(mx, fmaxf(fmaxf(t.x, t.y), fmaxf(t.z, t.w)));
    }

    // ---- Block min/max (+ zero hist in same phase) ----
    #pragma unroll
    for (int off = 32; off > 0; off >>= 1) {
        mn = fminf(mn, __shfl_down(mn, off, 64));
        mx = fmaxf(mx, __shfl_down(mx, off, 64));
    }
    if (lane == 0) { sm.fmin[wid] = mn; sm.fmax[wid] = mx; }
    #pragma unroll
    for (int j = 0; j < BPT; j++) sm.hist[tid + j * NT] = 0;
    __syncthreads();                                             // S1
    #pragma unroll
    for (int w = 0; w < NWAVE; w++) {
        mn = fminf(mn, sm.fmin[w]);
        mx = fmaxf(mx, sm.fmax[w]);
    }

    if (!(mx > mn)) {   // all values equal (uniform branch)
        if (tid == 0) { out[row] = mn; out[ROWS + row] = mn; }
        return;
    }
    const float scale1 = (float)NB / (mx - mn);

    // ---- L1 histogram; cache each value's bin packed 2x16b (8 VGPR) so the
    //      scatter pass doesn't recompute fma/cvt/clamp per value ----
    uint32_t binPk[VPT / 2];
    #pragma unroll
    for (int j = 0; j < VPT; j += 2) {
        int b0 = bin1f(v[j],     mn, scale1);
        int b1 = bin1f(v[j + 1], mn, scale1);
        binPk[j >> 1] = (uint32_t)b0 | ((uint32_t)b1 << 16);
        atomicAdd(&sm.hist[HIX(b0)], 1u);
        atomicAdd(&sm.hist[HIX(b1)], 1u);
    }
    __syncthreads();                                             // S2

    // ---- Single scan: locate rank bins + write scatter bases ----
    uint32_t h[BPT], s0 = 0;
    #pragma unroll
    for (int j = 0; j < BPT; j++) { h[j] = sm.hist[(j << 9) | tid]; s0 += h[j]; }
    uint32_t sc = s0;
    #pragma unroll
    for (int off = 1; off < 64; off <<= 1) {
        uint32_t n = __shfl_up(sc, off, 64);
        if (lane >= off) sc += n;
    }
    if (lane == 63) sm.wsum[wid] = sc;
    __syncthreads();                                             // S3
    uint32_t woff = 0;
    #pragma unroll
    for (int w = 0; w < NWAVE; w++) if (w < wid) woff += sm.wsum[w];
    const uint32_t incl = sc + woff, excl = incl - s0;
    const uint32_t ka = NW - 1, kb = TARGET - 1;
    if (ka >= excl && ka < incl) {           // bin of rank 512 (bottom tail end)
        uint32_t c = excl; bool done = false;
        #pragma unroll
        for (int j = 0; j < BPT; j++) {
            if (!done) {
                if (ka < c + h[j]) {
                    sm.res[0] = (uint32_t)(tid * BPT + j);
                    sm.res[1] = c + h[j];    // cntB = inclusive prefix at B_lo
                    done = true;
                } else c += h[j];
            }
        }
    }
    if (kb >= excl && kb < incl) {           // bin of rank 7679 (top tail start)
        uint32_t c = excl; bool done = false;
        #pragma unroll
        for (int j = 0; j < BPT; j++) {
            if (!done) {
                if (kb < c + h[j]) {
                    sm.res[2] = (uint32_t)(tid * BPT + j);
                    sm.res[3] = c;           // topBase = exclusive prefix at B_hi
                    done = true;
                } else c += h[j];
            }
        }
    }
    {   // overwrite counts with exclusive-prefix bases (independent of res)
        uint32_t run = excl;
        #pragma unroll
        for (int j = 0; j < BPT; j++) { sm.hist[(j << 9) | tid] = run; run += h[j]; }
    }
    __syncthreads();                                             // S4
    const int      B_lo    = (int)sm.res[0];
    const uint32_t cntB    = sm.res[1];
    const int      B_hi    = (int)sm.res[2];
    const uint32_t topBase = sm.res[3];
    const uint32_t shiftT  = cntB - topBase;     // mod-2^32; top slot = excl + shiftT
    uint32_t tot = cntB + (uint32_t)NCOL - topBase;
    if (tot > SCAP) tot = SCAP;

    // ---- Scatter candidates directly to global-rank slots (cached bins) ----
    #pragma unroll
    for (int j = 0; j < VPT; j++) {
        int b = (int)((binPk[j >> 1] >> ((j & 1) * 16)) & 0xffffu);
        if (b <= B_lo || b >= B_hi) {
            uint32_t pos = atomicAdd(&sm.hist[HIX(b)], 1u);
            if (b >= B_hi) pos += shiftT;
            if (pos < SCAP) sm.sorted[pos] = v[j];
        }
    }
    __syncthreads();                                             // S5
    // now hist[b] = exclusive prefix + count = inclusive end (unshifted for top)

    // ---- Fix-up: rank within L1 bins, write to sorted2 (no WB hazard) ----
    #pragma unroll
    for (int it = 0; it < MAXS; it++) {
        int s = tid + it * NT;
        if (s < (int)tot) {
            float vv = sm.sorted[s];
            int b = bin1f(vv, mn, scale1);
            uint32_t en = sm.hist[HIX(b)];
            uint32_t st;
            if (s < (int)cntB) {
                st = (b == 0) ? 0u : sm.hist[HIX(b - 1)];
            } else {
                st = (b == B_hi) ? topBase : sm.hist[HIX(b - 1)];
                st += shiftT; en += shiftT;
            }
            if (en > tot) en = tot;
            uint32_t r = 0;
            if (en - st > 1) {
                for (uint32_t q = st; q < en; q++) {
                    float u = sm.sorted[q];
                    r += (u < vv) || (u == vv && (int)q < s);
                }
            }
            uint32_t d = st + r;
            if (d < SCAP) sm.sorted2[d] = vv;
        }
    }
    __syncthreads();                                             // S6

    // sorted2[0..cntB) = global ranks 0..cntB-1; sorted2[cntB..tot) = top tail.
    // window i: left = sorted2[i]; right = sorted2[tot - NW + i]

    // ---- single-wave argmin: wave 0 reduces 513 windows (9/lane) with
    //      shuffles only -- no 8-wave phase, no rv/ri LDS, no extra barrier ----
    if (wid == 0) {
        const int topstart = (int)tot - NW;
        float lbest = __int_as_float(0x7F800000);   // +inf
        int   lidx  = 0x7FFFFFFF;
        for (int i = lane; i < NW; i += 64) {
            float len = sm.sorted2[topstart + i] - sm.sorted2[i];
            if (len < lbest) { lbest = len; lidx = i; }
        }
        #pragma unroll
        for (int off = 32; off > 0; off >>= 1) {
            float v2 = __shfl_down(lbest, off, 64);
            int   i2 = __shfl_down(lidx,  off, 64);
            if (v2 < lbest || (v2 == lbest && i2 < lidx)) { lbest = v2; lidx = i2; }
        }
        if (lane == 0) {
            out[row]        = sm.sorted2[lidx];             // left  = s[idx]
            out[ROWS + row] = sm.sorted2[topstart + lidx];  // right = s[idx+target-1]
        }
    }
}

extern "C" void kernel_launch(void* const* d_in, const int* in_sizes, int n_in,
                              void* d_out, int out_size, void* d_ws, size_t ws_size,
                              hipStream_t stream) {
    const float* x = (const float*)d_in[0];
    float* out = (float*)d_out;
    recall_window_kernel<<<ROWS, NT, 0, stream>>>(x, out);
}